// Round 4
// baseline (1382.948 us; speedup 1.0000x reference)
//
#include <hip/hip_runtime.h>
#include <hip/hip_fp16.h>
#include <math.h>

#define NN 100000
#define NE 3200000
#define FIN 256
#define HID 16
#define NC 32
#define NBUK 782          // ceil(NN/128), bucket = dst >> 7
#define SC_BLOCKS 500     // NE = 500 * 6400
#define SC_TILE 6400      // edges per binscatter block (25 per thread)

// ---------------------------------------------------------------------------
// K1: fused node GEMM for layer 1 (unchanged from round 3).
//   xs1p[n*16+c] = half2( x[n]@W1[0][:,c], x[n]@W1[1][:,c] )  (64 B/node)
//   r1[n*16+c]   = x[n]@root1[:,c] + bias1[c]                 (fp32)
// ---------------------------------------------------------------------------
__global__ __launch_bounds__(256) void k_gemm1(
    const float* __restrict__ x, const float* __restrict__ W1,
    const float* __restrict__ root1, const float* __restrict__ bias1,
    __half2* __restrict__ xs1p, float* __restrict__ r1)
{
    __shared__ float w[FIN * 48];   // 48 KiB
    for (int i = threadIdx.x; i < FIN * 48; i += 256) {
        int f = i / 48, j = i - f * 48;
        float v;
        if (j < 16)      v = W1[f * 16 + j];
        else if (j < 32) v = W1[FIN * 16 + f * 16 + (j - 16)];
        else             v = root1[f * 16 + (j - 32)];
        w[i] = v;
    }
    __syncthreads();

    int n0 = blockIdx.x * 512 + threadIdx.x;
    int n1 = n0 + 256;
    bool p0 = n0 < NN, p1 = n1 < NN;
    const float4* x0 = (const float4*)(x + (size_t)(p0 ? n0 : 0) * FIN);
    const float4* x1 = (const float4*)(x + (size_t)(p1 ? n1 : 0) * FIN);

    float acc0[48], acc1[48];
    #pragma unroll
    for (int o = 0; o < 48; ++o) { acc0[o] = 0.f; acc1[o] = 0.f; }

    const float4* wv = (const float4*)w;
    for (int q = 0; q < FIN / 4; ++q) {
        float4 a = x0[q];
        float4 b = x1[q];
        int base = q * 48;
        #pragma unroll
        for (int j = 0; j < 12; ++j) {
            float4 w0 = wv[base + j];
            float4 w1r = wv[base + 12 + j];
            float4 w2 = wv[base + 24 + j];
            float4 w3 = wv[base + 36 + j];
            int o = j * 4;
            acc0[o+0] += a.x*w0.x + a.y*w1r.x + a.z*w2.x + a.w*w3.x;
            acc0[o+1] += a.x*w0.y + a.y*w1r.y + a.z*w2.y + a.w*w3.y;
            acc0[o+2] += a.x*w0.z + a.y*w1r.z + a.z*w2.z + a.w*w3.z;
            acc0[o+3] += a.x*w0.w + a.y*w1r.w + a.z*w2.w + a.w*w3.w;
            acc1[o+0] += b.x*w0.x + b.y*w1r.x + b.z*w2.x + b.w*w3.x;
            acc1[o+1] += b.x*w0.y + b.y*w1r.y + b.z*w2.y + b.w*w3.y;
            acc1[o+2] += b.x*w0.z + b.y*w1r.z + b.z*w2.z + b.w*w3.z;
            acc1[o+3] += b.x*w0.w + b.y*w1r.w + b.z*w2.w + b.w*w3.w;
        }
    }
    if (p0) {
        __half2* xs = xs1p + (size_t)n0 * 16;
        float* rr = r1 + (size_t)n0 * 16;
        #pragma unroll
        for (int c = 0; c < 16; ++c) xs[c] = __floats2half2_rn(acc0[c], acc0[16 + c]);
        #pragma unroll
        for (int c = 0; c < 16; ++c) rr[c] = acc0[32 + c] + bias1[c];
    }
    if (p1) {
        __half2* xs = xs1p + (size_t)n1 * 16;
        float* rr = r1 + (size_t)n1 * 16;
        #pragma unroll
        for (int c = 0; c < 16; ++c) xs[c] = __floats2half2_rn(acc1[c], acc1[16 + c]);
        #pragma unroll
        for (int c = 0; c < 16; ++c) rr[c] = acc1[32 + c] + bias1[c];
    }
}

// ---------------------------------------------------------------------------
// Bucket histogram: LDS-merged counts of dst>>7.
// ---------------------------------------------------------------------------
__global__ __launch_bounds__(256) void k_bhist(const int* __restrict__ ei,
                                               int* __restrict__ bhist)
{
    __shared__ int h[NBUK];
    int t = threadIdx.x;
    for (int b = t; b < NBUK; b += 256) h[b] = 0;
    __syncthreads();
    int e0 = blockIdx.x * SC_TILE;
    #pragma unroll
    for (int k = 0; k < 25; ++k) {
        int e = e0 + t + k * 256;
        atomicAdd(&h[ei[NE + e] >> 7], 1);
    }
    __syncthreads();
    for (int b = t; b < NBUK; b += 256) {
        int c = h[b];
        if (c) atomicAdd(&bhist[b], c);
    }
}

// ---------------------------------------------------------------------------
// Exclusive scan of the 782 bucket counts (single 1024-thread block).
// Writes bstart (pristine) and gcur (mutable cursors for binscatter).
// ---------------------------------------------------------------------------
__global__ __launch_bounds__(1024) void k_bscan(const int* __restrict__ bhist,
                                                int* __restrict__ bstart,
                                                int* __restrict__ gcur)
{
    __shared__ int s[1024];
    int t = threadIdx.x;
    int v = (t < NBUK) ? bhist[t] : 0;
    s[t] = v;
    __syncthreads();
    for (int off = 1; off < 1024; off <<= 1) {
        int a = (t >= off) ? s[t - off] : 0;
        __syncthreads();
        s[t] += a;
        __syncthreads();
    }
    if (t < NBUK) {
        int excl = s[t] - v;
        bstart[t] = excl;
        gcur[t] = excl;
    }
}

// ---------------------------------------------------------------------------
// Binscatter: per-block per-bucket run reservation -> contiguous run writes.
// Record: .x = src | (dst&127)<<17 ; .y = f32 bits of clipped u.
// ---------------------------------------------------------------------------
__global__ __launch_bounds__(256) void k_binscatter(
    const int* __restrict__ ei, const float* __restrict__ ea,
    int* __restrict__ gcur, uint2* __restrict__ rec)
{
    __shared__ int h[NBUK];
    int t = threadIdx.x;
    for (int b = t; b < NBUK; b += 256) h[b] = 0;
    __syncthreads();
    int e0 = blockIdx.x * SC_TILE;
    #pragma unroll
    for (int k = 0; k < 25; ++k) {
        int e = e0 + t + k * 256;
        atomicAdd(&h[ei[NE + e] >> 7], 1);
    }
    __syncthreads();
    for (int b = t; b < NBUK; b += 256)
        h[b] = atomicAdd(&gcur[b], h[b]);     // LDS now holds block-local cursors
    __syncthreads();
    #pragma unroll
    for (int k = 0; k < 25; ++k) {
        int e = e0 + t + k * 256;
        int src = ei[e];
        int dst = ei[NE + e];
        float u = fminf(fmaxf(ea[e], 0.f), 1.f);
        int pos = atomicAdd(&h[dst >> 7], 1);
        uint2 r;
        r.x = (unsigned)src | ((unsigned)(dst & 127) << 17);
        r.y = __float_as_uint(u);
        rec[pos] = r;
    }
}

// ---------------------------------------------------------------------------
// Agg layer 1 + fused layer-2 node GEMM. One block per 128-node bucket.
// Main loop: 32 record-slots x 8 lanes; lane j owns channels (2j, 2j+1);
// fp32 LDS accumulators acc[128][17] (pad kills bank conflicts).
// Epilogue: h = elu(acc/max(cnt,1)+r1) in regs, then hs2p/r2 = h @ {W2,root2}.
// ---------------------------------------------------------------------------
__global__ __launch_bounds__(256) void k_agg1g2(
    const int* __restrict__ bstart, const int* __restrict__ bhist,
    const uint2* __restrict__ rec, const uint2* __restrict__ xs,
    const float* __restrict__ r1,
    const float* __restrict__ W2, const float* __restrict__ root2,
    const float* __restrict__ bias2,
    __half2* __restrict__ hs2p, float* __restrict__ r2)
{
    __shared__ float acc[128 * 17];
    __shared__ int cnt[128];
    __shared__ float wgt[1568];   // W2[1024] | root2[512] | bias2[32]
    int t = threadIdx.x;
    for (int i = t; i < 128 * 17; i += 256) acc[i] = 0.f;
    if (t < 128) cnt[t] = 0;
    for (int i = t; i < 1568; i += 256)
        wgt[i] = (i < 1024) ? W2[i] : (i < 1536 ? root2[i - 1024] : bias2[i - 1536]);
    __syncthreads();

    int slot = t >> 3, j = t & 7;
    int start = bstart[blockIdx.x];
    int cntE = bhist[blockIdx.x];

    #define PROC1(r, g) {                                              \
        int dl = (int)((r).x >> 17) & 127;                             \
        float u = __uint_as_float((r).y);                              \
        float2 f0 = __half22float2(*(const __half2*)&(g).x);           \
        float2 f1 = __half22float2(*(const __half2*)&(g).y);           \
        atomicAdd(&acc[dl * 17 + 2 * j],     (1.f - u) * f0.x + u * f0.y); \
        atomicAdd(&acc[dl * 17 + 2 * j + 1], (1.f - u) * f1.x + u * f1.y); \
        if (j == 0) atomicAdd(&cnt[dl], 1); }

    int bi = 0;
    for (; bi + 128 <= cntE; bi += 128) {
        int i0 = start + bi + slot;
        uint2 ra = rec[i0], rb = rec[i0 + 32], rc = rec[i0 + 64], rd = rec[i0 + 96];
        uint2 ga = xs[(size_t)(ra.x & 0x1FFFF) * 8 + j];
        uint2 gb = xs[(size_t)(rb.x & 0x1FFFF) * 8 + j];
        uint2 gc = xs[(size_t)(rc.x & 0x1FFFF) * 8 + j];
        uint2 gd = xs[(size_t)(rd.x & 0x1FFFF) * 8 + j];
        PROC1(ra, ga) PROC1(rb, gb) PROC1(rc, gc) PROC1(rd, gd)
    }
    for (int i = start + bi + slot; i < start + cntE; i += 32) {
        uint2 r = rec[i];
        uint2 g = xs[(size_t)(r.x & 0x1FFFF) * 8 + j];
        PROC1(r, g)
    }
    #undef PROC1
    __syncthreads();

    if (t < 128) {
        int n = blockIdx.x * 128 + t;
        if (n < NN) {
            float inv = 1.f / fmaxf((float)cnt[t], 1.f);
            const float* r1p = r1 + (size_t)n * 16;
            float h[16];
            #pragma unroll
            for (int c = 0; c < 16; ++c) {
                float v = acc[t * 17 + c] * inv + r1p[c];
                h[c] = v > 0.f ? v : expm1f(v);
            }
            __half2* hp = hs2p + (size_t)n * 32;
            float* r2p = r2 + (size_t)n * 32;
            #pragma unroll
            for (int c = 0; c < 32; ++c) {
                float d0 = 0.f, d1 = 0.f, dr = wgt[1536 + c];
                #pragma unroll
                for (int k = 0; k < 16; ++k) {
                    d0 += h[k] * wgt[k * 32 + c];
                    d1 += h[k] * wgt[512 + k * 32 + c];
                    dr += h[k] * wgt[1024 + k * 32 + c];
                }
                hp[c] = __floats2half2_rn(d0, d1);
                r2p[c] = dr;
            }
        }
    }
}

// ---------------------------------------------------------------------------
// Agg layer 2 + fused mean/root/log-softmax epilogue -> d_out.
// 16 record-slots x 16 lanes; acc[128][33].
// ---------------------------------------------------------------------------
__global__ __launch_bounds__(256) void k_agg2(
    const int* __restrict__ bstart, const int* __restrict__ bhist,
    const uint2* __restrict__ rec, const uint2* __restrict__ hs,
    const float* __restrict__ r2, float* __restrict__ out)
{
    __shared__ float acc[128 * 33];
    __shared__ int cnt[128];
    int t = threadIdx.x;
    for (int i = t; i < 128 * 33; i += 256) acc[i] = 0.f;
    if (t < 128) cnt[t] = 0;
    __syncthreads();

    int slot = t >> 4, j = t & 15;
    int start = bstart[blockIdx.x];
    int cntE = bhist[blockIdx.x];

    #define PROC2(r, g) {                                              \
        int dl = (int)((r).x >> 17) & 127;                             \
        float u = __uint_as_float((r).y);                              \
        float2 f0 = __half22float2(*(const __half2*)&(g).x);           \
        float2 f1 = __half22float2(*(const __half2*)&(g).y);           \
        atomicAdd(&acc[dl * 33 + 2 * j],     (1.f - u) * f0.x + u * f0.y); \
        atomicAdd(&acc[dl * 33 + 2 * j + 1], (1.f - u) * f1.x + u * f1.y); \
        if (j == 0) atomicAdd(&cnt[dl], 1); }

    int bi = 0;
    for (; bi + 64 <= cntE; bi += 64) {
        int i0 = start + bi + slot;
        uint2 ra = rec[i0], rb = rec[i0 + 16], rc = rec[i0 + 32], rd = rec[i0 + 48];
        uint2 ga = hs[(size_t)(ra.x & 0x1FFFF) * 16 + j];
        uint2 gb = hs[(size_t)(rb.x & 0x1FFFF) * 16 + j];
        uint2 gc = hs[(size_t)(rc.x & 0x1FFFF) * 16 + j];
        uint2 gd = hs[(size_t)(rd.x & 0x1FFFF) * 16 + j];
        PROC2(ra, ga) PROC2(rb, gb) PROC2(rc, gc) PROC2(rd, gd)
    }
    for (int i = start + bi + slot; i < start + cntE; i += 16) {
        uint2 r = rec[i];
        uint2 g = hs[(size_t)(r.x & 0x1FFFF) * 16 + j];
        PROC2(r, g)
    }
    #undef PROC2
    __syncthreads();

    if (t < 128) {
        int n = blockIdx.x * 128 + t;
        if (n < NN) {
            float inv = 1.f / fmaxf((float)cnt[t], 1.f);
            const float* r2p = r2 + (size_t)n * 32;
            float v[32];
            float m = -1e30f;
            #pragma unroll
            for (int c = 0; c < 32; ++c) {
                v[c] = acc[t * 33 + c] * inv + r2p[c];
                m = fmaxf(m, v[c]);
            }
            float s = 0.f;
            #pragma unroll
            for (int c = 0; c < 32; ++c) s += expf(v[c] - m);
            float ls = m + logf(s);
            float* op = out + (size_t)n * 32;
            #pragma unroll
            for (int c = 0; c < 32; ++c) op[c] = v[c] - ls;
        }
    }
}

// ---------------------------------------------------------------------------
extern "C" void kernel_launch(void* const* d_in, const int* in_sizes, int n_in,
                              void* d_out, int out_size, void* d_ws, size_t ws_size,
                              hipStream_t stream)
{
    const float* x     = (const float*)d_in[0];
    const float* ea    = (const float*)d_in[1];
    const float* W1    = (const float*)d_in[2];
    const float* root1 = (const float*)d_in[3];
    const float* bias1 = (const float*)d_in[4];
    const float* W2    = (const float*)d_in[5];
    const float* root2 = (const float*)d_in[6];
    const float* bias2 = (const float*)d_in[7];
    const int*   ei    = (const int*)d_in[8];
    float* out = (float*)d_out;

    // Workspace layout (float units):
    float* ws = (float*)d_ws;
    __half2* xs1p = (__half2*)ws;                      // NN*16 half2 = NN*16 fl
    float*   r1   = ws + (size_t)NN * 16;              // NN*16 fl
    __half2* hs2p = (__half2*)(ws + (size_t)NN * 32);  // NN*32 half2 = NN*32 fl
    float*   r2   = ws + (size_t)NN * 64;              // NN*32 fl
    uint2*   rec  = (uint2*)(ws + (size_t)NN * 96);    // NE uint2 = NN*64 fl
    int*     iws  = (int*)(ws + (size_t)NN * 160);
    int* bhist  = iws;                 // NBUK
    int* bstart = iws + NBUK;          // NBUK
    int* gcur   = iws + 2 * NBUK;      // NBUK
    // total = NN*160 floats + ~9.4 KB = 64.0 MB

    hipMemsetAsync(bhist, 0, NBUK * sizeof(int), stream);

    k_gemm1<<<(NN + 511) / 512, 256, 0, stream>>>(x, W1, root1, bias1, xs1p, r1);
    k_bhist<<<SC_BLOCKS, 256, 0, stream>>>(ei, bhist);
    k_bscan<<<1, 1024, 0, stream>>>(bhist, bstart, gcur);
    k_binscatter<<<SC_BLOCKS, 256, 0, stream>>>(ei, ea, gcur, rec);
    k_agg1g2<<<NBUK, 256, 0, stream>>>(bstart, bhist, rec, (const uint2*)xs1p,
                                       r1, W2, root2, bias2, hs2p, r2);
    k_agg2<<<NBUK, 256, 0, stream>>>(bstart, bhist, rec, (const uint2*)hs2p,
                                     r2, out);
}

// Round 5
// 501.685 us; speedup vs baseline: 2.7566x; 2.7566x over previous
//
#include <hip/hip_runtime.h>
#include <hip/hip_fp16.h>
#include <math.h>

#define NN 100000
#define NE 3200000
#define FIN 256
#define HID 16
#define NC 32
#define NBUK 782          // ceil(NN/128); bucket = dst >> 7
#define SC_BLOCKS 250
#define SC_TILE 12800     // NE = 250 * 12800; 50 edges/thread
#define SC_EPT 50
#define SK 26             // sort staging regs: 26*256=6656 >> mean 4092 (+40 sigma)

// ---------------------------------------------------------------------------
// K1: fused node GEMM for layer 1.
//   xs1p[n*16+c] = half2( x[n]@W1[0][:,c], x[n]@W1[1][:,c] )  (64 B/node)
//   r1h[n*8+w]   = half2( r1[2w], r1[2w+1] ),  r1 = x[n]@root1 + bias1
// ---------------------------------------------------------------------------
__global__ __launch_bounds__(256) void k_gemm1(
    const float* __restrict__ x, const float* __restrict__ W1,
    const float* __restrict__ root1, const float* __restrict__ bias1,
    __half2* __restrict__ xs1p, __half2* __restrict__ r1h)
{
    __shared__ float w[FIN * 48];   // 48 KiB
    for (int i = threadIdx.x; i < FIN * 48; i += 256) {
        int f = i / 48, j = i - f * 48;
        float v;
        if (j < 16)      v = W1[f * 16 + j];
        else if (j < 32) v = W1[FIN * 16 + f * 16 + (j - 16)];
        else             v = root1[f * 16 + (j - 32)];
        w[i] = v;
    }
    __syncthreads();

    int n0 = blockIdx.x * 512 + threadIdx.x;
    int n1 = n0 + 256;
    bool p0 = n0 < NN, p1 = n1 < NN;
    const float4* x0 = (const float4*)(x + (size_t)(p0 ? n0 : 0) * FIN);
    const float4* x1 = (const float4*)(x + (size_t)(p1 ? n1 : 0) * FIN);

    float acc0[48], acc1[48];
    #pragma unroll
    for (int o = 0; o < 48; ++o) { acc0[o] = 0.f; acc1[o] = 0.f; }

    const float4* wv = (const float4*)w;
    for (int q = 0; q < FIN / 4; ++q) {
        float4 a = x0[q];
        float4 b = x1[q];
        int base = q * 48;
        #pragma unroll
        for (int j = 0; j < 12; ++j) {
            float4 w0 = wv[base + j];
            float4 w1r = wv[base + 12 + j];
            float4 w2 = wv[base + 24 + j];
            float4 w3 = wv[base + 36 + j];
            int o = j * 4;
            acc0[o+0] += a.x*w0.x + a.y*w1r.x + a.z*w2.x + a.w*w3.x;
            acc0[o+1] += a.x*w0.y + a.y*w1r.y + a.z*w2.y + a.w*w3.y;
            acc0[o+2] += a.x*w0.z + a.y*w1r.z + a.z*w2.z + a.w*w3.z;
            acc0[o+3] += a.x*w0.w + a.y*w1r.w + a.z*w2.w + a.w*w3.w;
            acc1[o+0] += b.x*w0.x + b.y*w1r.x + b.z*w2.x + b.w*w3.x;
            acc1[o+1] += b.x*w0.y + b.y*w1r.y + b.z*w2.y + b.w*w3.y;
            acc1[o+2] += b.x*w0.z + b.y*w1r.z + b.z*w2.z + b.w*w3.z;
            acc1[o+3] += b.x*w0.w + b.y*w1r.w + b.z*w2.w + b.w*w3.w;
        }
    }
    if (p0) {
        __half2* xs = xs1p + (size_t)n0 * 16;
        __half2* rr = r1h + (size_t)n0 * 8;
        #pragma unroll
        for (int c = 0; c < 16; ++c) xs[c] = __floats2half2_rn(acc0[c], acc0[16 + c]);
        #pragma unroll
        for (int c = 0; c < 8; ++c)
            rr[c] = __floats2half2_rn(acc0[32 + 2*c] + bias1[2*c],
                                      acc0[33 + 2*c] + bias1[2*c + 1]);
    }
    if (p1) {
        __half2* xs = xs1p + (size_t)n1 * 16;
        __half2* rr = r1h + (size_t)n1 * 8;
        #pragma unroll
        for (int c = 0; c < 16; ++c) xs[c] = __floats2half2_rn(acc1[c], acc1[16 + c]);
        #pragma unroll
        for (int c = 0; c < 8; ++c)
            rr[c] = __floats2half2_rn(acc1[32 + 2*c] + bias1[2*c],
                                      acc1[33 + 2*c] + bias1[2*c + 1]);
    }
}

// ---------------------------------------------------------------------------
// Bucket histogram (LDS-merged counts of dst>>7).
// ---------------------------------------------------------------------------
__global__ __launch_bounds__(256) void k_bhist(const int* __restrict__ ei,
                                               int* __restrict__ bhist)
{
    __shared__ int h[NBUK];
    int t = threadIdx.x;
    for (int b = t; b < NBUK; b += 256) h[b] = 0;
    __syncthreads();
    const int* dstp = ei + NE + blockIdx.x * SC_TILE;
    for (int k = 0; k < SC_EPT; ++k)
        atomicAdd(&h[dstp[t + k * 256] >> 7], 1);
    __syncthreads();
    for (int b = t; b < NBUK; b += 256) {
        int c = h[b];
        if (c) atomicAdd(&bhist[b], c);
    }
}

// ---------------------------------------------------------------------------
// Exclusive scan of 782 bucket counts; writes bstart (pristine), gcur
// (mutable cursors), and the rowptr sentinel.
// ---------------------------------------------------------------------------
__global__ __launch_bounds__(1024) void k_bscan(const int* __restrict__ bhist,
                                                int* __restrict__ bstart,
                                                int* __restrict__ gcur,
                                                int* __restrict__ rowptr)
{
    __shared__ int s[1024];
    int t = threadIdx.x;
    int v = (t < NBUK) ? bhist[t] : 0;
    s[t] = v;
    __syncthreads();
    for (int off = 1; off < 1024; off <<= 1) {
        int a = (t >= off) ? s[t - off] : 0;
        __syncthreads();
        s[t] += a;
        __syncthreads();
    }
    if (t < NBUK) {
        int excl = s[t] - v;
        bstart[t] = excl;
        gcur[t] = excl;
    }
    if (t == 0) rowptr[NN] = NE;
}

// ---------------------------------------------------------------------------
// Binscatter: per-block per-bucket run reservation -> contiguous run writes.
// Record: .x = src | (dst&127)<<17 ; .y = f32 bits of clipped u.
// Runs avg 131 B and are block-private => no cross-XCD line bouncing.
// ---------------------------------------------------------------------------
__global__ __launch_bounds__(256) void k_binscatter(
    const int* __restrict__ ei, const float* __restrict__ ea,
    int* __restrict__ gcur, uint2* __restrict__ rec)
{
    __shared__ int h[NBUK];
    int t = threadIdx.x;
    for (int b = t; b < NBUK; b += 256) h[b] = 0;
    __syncthreads();
    int e0 = blockIdx.x * SC_TILE;
    for (int k = 0; k < SC_EPT; ++k)
        atomicAdd(&h[ei[NE + e0 + t + k * 256] >> 7], 1);
    __syncthreads();
    for (int b = t; b < NBUK; b += 256)
        h[b] = atomicAdd(&gcur[b], h[b]);   // LDS now holds global cursors
    __syncthreads();
    for (int k = 0; k < SC_EPT; ++k) {
        int e = e0 + t + k * 256;
        int src = ei[e];
        int dst = ei[NE + e];
        float u = fminf(fmaxf(ea[e], 0.f), 1.f);
        int pos = atomicAdd(&h[dst >> 7], 1);
        uint2 r;
        r.x = (unsigned)src | ((unsigned)(dst & 127) << 17);
        r.y = __float_as_uint(u);
        rec[pos] = r;
    }
}

// ---------------------------------------------------------------------------
// In-bucket counting sort (in place) -> full per-node CSR. One block/bucket.
// Stage records in registers, LDS 128-counter histogram + scan, rewrite.
// Also emits rowptr (deg[n] = rowptr[n+1]-rowptr[n]).
// ---------------------------------------------------------------------------
__global__ __launch_bounds__(256) void k_sort(
    const int* __restrict__ bstart, const int* __restrict__ bhist,
    uint2* __restrict__ rec, int* __restrict__ rowptr)
{
    __shared__ int cnt[128], cur[128], ss[128];
    int t = threadIdx.x;
    if (t < 128) cnt[t] = 0;
    __syncthreads();
    int start = bstart[blockIdx.x], m = bhist[blockIdx.x];
    uint2 r[SK];
    int nr = 0;
    for (int i = start + t; i < start + m; i += 256) {
        uint2 v = rec[i];
        if (nr < SK) r[nr++] = v;
        atomicAdd(&cnt[(v.x >> 17) & 127], 1);
    }
    __syncthreads();
    if (t < 128) ss[t] = cnt[t];
    __syncthreads();
    for (int off = 1; off < 128; off <<= 1) {
        int a = (t < 128 && t >= off) ? ss[t - off] : 0;
        __syncthreads();
        if (t < 128) ss[t] += a;
        __syncthreads();
    }
    if (t < 128) {
        int excl = ss[t] - cnt[t];
        cur[t] = excl;
        int n = blockIdx.x * 128 + t;
        if (n < NN) rowptr[n] = start + excl;
    }
    __syncthreads();
    for (int k = 0; k < nr; ++k) {
        int dl = (int)(r[k].x >> 17) & 127;
        int p = atomicAdd(&cur[dl], 1);
        rec[start + p] = r[k];
    }
}

// ---------------------------------------------------------------------------
// Agg layer 1 (register accumulation, 8 lanes/node, 4-deep gather batching)
// + fused ELU + layer-2 node GEMM epilogue.
// ---------------------------------------------------------------------------
__global__ __launch_bounds__(256) void k_agg1g2(
    const int* __restrict__ rowptr, const uint2* __restrict__ rec,
    const uint2* __restrict__ xs, const __half2* __restrict__ r1h,
    const float* __restrict__ W2, const float* __restrict__ root2,
    const float* __restrict__ bias2,
    __half2* __restrict__ hs2p, float* __restrict__ r2)
{
    __shared__ float hsm[32 * 17];
    __shared__ float wgt[1568];   // W2[1024] | root2[512] | bias2[32]
    int t = threadIdx.x;
    for (int i = t; i < 1568; i += 256)
        wgt[i] = (i < 1024) ? W2[i] : (i < 1536 ? root2[i - 1024] : bias2[i - 1536]);

    int nl = t >> 3, j = t & 7;
    int n = blockIdx.x * 32 + nl;          // grid 3125: n < NN always
    int s = rowptr[n], e = rowptr[n + 1];
    int d = e - s;
    float a0 = 0.f, a1 = 0.f;

    #define ACC1(q, g) {                                            \
        float u = __uint_as_float((q).y);                           \
        float2 f0 = __half22float2(*(const __half2*)&(g).x);        \
        float2 f1 = __half22float2(*(const __half2*)&(g).y);        \
        a0 += (1.f - u) * f0.x + u * f0.y;                          \
        a1 += (1.f - u) * f1.x + u * f1.y; }

    int k = s;
    for (; k + 4 <= e; k += 4) {
        uint2 q0 = rec[k], q1 = rec[k+1], q2 = rec[k+2], q3 = rec[k+3];
        uint2 g0 = xs[(size_t)(q0.x & 0x1FFFF) * 8 + j];
        uint2 g1 = xs[(size_t)(q1.x & 0x1FFFF) * 8 + j];
        uint2 g2 = xs[(size_t)(q2.x & 0x1FFFF) * 8 + j];
        uint2 g3 = xs[(size_t)(q3.x & 0x1FFFF) * 8 + j];
        ACC1(q0, g0) ACC1(q1, g1) ACC1(q2, g2) ACC1(q3, g3)
    }
    for (; k < e; ++k) {
        uint2 q = rec[k];
        uint2 g = xs[(size_t)(q.x & 0x1FFFF) * 8 + j];
        ACC1(q, g)
    }
    #undef ACC1

    float inv = 1.f / fmaxf((float)d, 1.f);
    float2 rr = __half22float2(r1h[(size_t)n * 8 + j]);
    float v0 = a0 * inv + rr.x;
    float v1 = a1 * inv + rr.y;
    v0 = v0 > 0.f ? v0 : expm1f(v0);
    v1 = v1 > 0.f ? v1 : expm1f(v1);
    hsm[nl * 17 + 2 * j] = v0;
    hsm[nl * 17 + 2 * j + 1] = v1;
    __syncthreads();

    float h[16];
    #pragma unroll
    for (int kk = 0; kk < 16; ++kk) h[kk] = hsm[nl * 17 + kk];
    __half2* hp = hs2p + (size_t)n * 32;
    float* r2p = r2 + (size_t)n * 32;
    #pragma unroll
    for (int mo = 0; mo < 4; ++mo) {
        int c = j + 8 * mo;
        float d0 = 0.f, d1 = 0.f, dr = wgt[1536 + c];
        #pragma unroll
        for (int kk = 0; kk < 16; ++kk) {
            d0 += h[kk] * wgt[kk * 32 + c];
            d1 += h[kk] * wgt[512 + kk * 32 + c];
            dr += h[kk] * wgt[1024 + kk * 32 + c];
        }
        hp[c] = __floats2half2_rn(d0, d1);
        r2p[c] = dr;
    }
}

// ---------------------------------------------------------------------------
// Agg layer 2 (register accumulation, 16 lanes/node) + fused mean + root +
// log-softmax epilogue -> d_out.
// ---------------------------------------------------------------------------
__global__ __launch_bounds__(256) void k_agg2(
    const int* __restrict__ rowptr, const uint2* __restrict__ rec,
    const uint2* __restrict__ hs, const float* __restrict__ r2,
    float* __restrict__ out)
{
    int t = threadIdx.x;
    int nl = t >> 4, j = t & 15;
    int n = blockIdx.x * 16 + nl;          // grid 6250: n < NN always
    int s = rowptr[n], e = rowptr[n + 1];
    int d = e - s;
    float a0 = 0.f, a1 = 0.f;

    #define ACC2(q, g) {                                            \
        float u = __uint_as_float((q).y);                           \
        float2 f0 = __half22float2(*(const __half2*)&(g).x);        \
        float2 f1 = __half22float2(*(const __half2*)&(g).y);        \
        a0 += (1.f - u) * f0.x + u * f0.y;                          \
        a1 += (1.f - u) * f1.x + u * f1.y; }

    int k = s;
    for (; k + 4 <= e; k += 4) {
        uint2 q0 = rec[k], q1 = rec[k+1], q2 = rec[k+2], q3 = rec[k+3];
        uint2 g0 = hs[(size_t)(q0.x & 0x1FFFF) * 16 + j];
        uint2 g1 = hs[(size_t)(q1.x & 0x1FFFF) * 16 + j];
        uint2 g2 = hs[(size_t)(q2.x & 0x1FFFF) * 16 + j];
        uint2 g3 = hs[(size_t)(q3.x & 0x1FFFF) * 16 + j];
        ACC2(q0, g0) ACC2(q1, g1) ACC2(q2, g2) ACC2(q3, g3)
    }
    for (; k < e; ++k) {
        uint2 q = rec[k];
        uint2 g = hs[(size_t)(q.x & 0x1FFFF) * 16 + j];
        ACC2(q, g)
    }
    #undef ACC2

    float inv = 1.f / fmaxf((float)d, 1.f);
    float2 rr = ((const float2*)r2)[(size_t)n * 16 + j];
    float v0 = a0 * inv + rr.x;
    float v1 = a1 * inv + rr.y;

    float m = fmaxf(v0, v1);
    #pragma unroll
    for (int off = 1; off < 16; off <<= 1)
        m = fmaxf(m, __shfl_xor(m, off, 16));
    float sm = expf(v0 - m) + expf(v1 - m);
    #pragma unroll
    for (int off = 1; off < 16; off <<= 1)
        sm += __shfl_xor(sm, off, 16);
    float ls = logf(sm);
    ((float2*)out)[(size_t)n * 16 + j] = make_float2(v0 - m - ls, v1 - m - ls);
}

// ---------------------------------------------------------------------------
extern "C" void kernel_launch(void* const* d_in, const int* in_sizes, int n_in,
                              void* d_out, int out_size, void* d_ws, size_t ws_size,
                              hipStream_t stream)
{
    const float* x     = (const float*)d_in[0];
    const float* ea    = (const float*)d_in[1];
    const float* W1    = (const float*)d_in[2];
    const float* root1 = (const float*)d_in[3];
    const float* bias1 = (const float*)d_in[4];
    const float* W2    = (const float*)d_in[5];
    const float* root2 = (const float*)d_in[6];
    const float* bias2 = (const float*)d_in[7];
    const int*   ei    = (const int*)d_in[8];
    float* out = (float*)d_out;

    // Workspace layout (float units; half2 = 4 B):
    float* ws = (float*)d_ws;
    __half2* xs1p = (__half2*)ws;                      // NN*16 fl
    __half2* r1h  = (__half2*)(ws + (size_t)NN * 16);  // NN*8  fl
    __half2* hs2p = (__half2*)(ws + (size_t)NN * 24);  // NN*32 fl
    float*   r2   = ws + (size_t)NN * 56;              // NN*32 fl
    uint2*   rec  = (uint2*)(ws + (size_t)NN * 88);    // NE uint2 = NN*64 fl
    int*     iws  = (int*)(ws + (size_t)NN * 152);
    int* rowptr = iws;                   // NN+1
    int* bhist  = iws + NN + 1;          // NBUK
    int* bstart = bhist + NBUK;          // NBUK
    int* gcur   = bstart + NBUK;         // NBUK
    // total ≈ NN*153 floats + 9.4 KB ≈ 61.2 MB

    hipMemsetAsync(bhist, 0, NBUK * sizeof(int), stream);

    k_gemm1<<<(NN + 511) / 512, 256, 0, stream>>>(x, W1, root1, bias1, xs1p, r1h);
    k_bhist<<<SC_BLOCKS, 256, 0, stream>>>(ei, bhist);
    k_bscan<<<1, 1024, 0, stream>>>(bhist, bstart, gcur, rowptr);
    k_binscatter<<<SC_BLOCKS, 256, 0, stream>>>(ei, ea, gcur, rec);
    k_sort<<<NBUK, 256, 0, stream>>>(bstart, bhist, rec, rowptr);
    k_agg1g2<<<(NN * 8) / 256, 256, 0, stream>>>(rowptr, rec, (const uint2*)xs1p,
                                                 r1h, W2, root2, bias2, hs2p, r2);
    k_agg2<<<(NN * 16) / 256, 256, 0, stream>>>(rowptr, rec, (const uint2*)hs2p,
                                                r2, out);
}